// Round 9
// baseline (972.544 us; speedup 1.0000x reference)
//
#include <hip/hip_runtime.h>
#include <hip/hip_bf16.h>
#include <math.h>

#define NQ   8192
#define NM   16384
#define DIM  1024
#define KNN  5

// ---------------- fast path config ----------------
#define SPLITS 16
#define SLICE  (NM / SPLITS)      // 1024
#define BM     128                // mem rows per tile
#define BN     128                // query cols per block
#define TILES  (SLICE / BM)       // 8
#define BK     32
#define KSTEPS (DIM / BK)         // 32
#define UNITS  (TILES * KSTEPS)   // 256 stage units per block
#define TPB1   256                // 4 waves
#define CPQ    (SPLITS * 8 * 5)   // 640 candidates per query

typedef float  f32x4_t  __attribute__((ext_vector_type(4)));
typedef __bf16 bf16x8_t __attribute__((ext_vector_type(8)));

typedef __attribute__((address_space(1))) unsigned int gu32_t;
typedef __attribute__((address_space(3))) unsigned int lu32_t;

__device__ __forceinline__ void gl16(const void* g, void* l) {
    __builtin_amdgcn_global_load_lds((gu32_t*)g, (lu32_t*)l, 16, 0, 0);
}

// ---------------- fast: mem f32 -> bf16 convert + squared norms (fused) ----------------
__global__ void cvt_m2_kernel(const float* __restrict__ mem,
                              __hip_bfloat16* __restrict__ out,
                              float* __restrict__ m2) {
    const int row  = blockIdx.x * 4 + (threadIdx.x >> 6);
    const int lane = threadIdx.x & 63;
    const float4* p = reinterpret_cast<const float4*>(mem + (size_t)row * DIM + lane * 16);
    float s = 0.f;
#pragma unroll
    for (int h = 0; h < 2; ++h) {
        const float4 a = p[2 * h];
        const float4 b = p[2 * h + 1];
        bf16x8_t v;
        v[0] = (__bf16)a.x; v[1] = (__bf16)a.y; v[2] = (__bf16)a.z; v[3] = (__bf16)a.w;
        v[4] = (__bf16)b.x; v[5] = (__bf16)b.y; v[6] = (__bf16)b.z; v[7] = (__bf16)b.w;
        reinterpret_cast<bf16x8_t*>(out + (size_t)row * DIM + lane * 16)[h] = v;
        s += a.x * a.x + a.y * a.y + a.z * a.z + a.w * a.w;
        s += b.x * b.x + b.y * b.y + b.z * b.z + b.w * b.w;
    }
#pragma unroll
    for (int off = 32; off > 0; off >>= 1) s += __shfl_down(s, off);
    if (lane == 0) m2[row] = s;
}

// ---------------- fast: query f32 -> bf16 convert ----------------
__global__ void cvt_bf16_kernel(const float* __restrict__ in,
                                __hip_bfloat16* __restrict__ out, int n8) {
    const int i = blockIdx.x * blockDim.x + threadIdx.x;
    if (i >= n8) return;
    const float4 a = reinterpret_cast<const float4*>(in)[2 * i];
    const float4 b = reinterpret_cast<const float4*>(in)[2 * i + 1];
    bf16x8_t v;
    v[0] = (__bf16)a.x; v[1] = (__bf16)a.y; v[2] = (__bf16)a.z; v[3] = (__bf16)a.w;
    v[4] = (__bf16)b.x; v[5] = (__bf16)b.y; v[6] = (__bf16)b.z; v[7] = (__bf16)b.w;
    reinterpret_cast<bf16x8_t*>(out)[i] = v;
}

// ---------------- fast phase 1: transposed GEMM + in-register top-5 ----------------
// R9 = R8 with __launch_bounds__(256, 4). R8 post-mortem: occupancy tracked the
// declared waves/EU every round (k = w*4/(B/64)); (256,2) pinned us to 2 blocks/CU.
// (256,4) -> 4 blocks/CU = 16 waves/CU at 0.5 ds_reads/MFMA, VGPR budget 128 >= 80.
// Everything else identical: BK=32 dbuf (36 KB LDS), R7 swizzle (0 conflicts),
// counted vmcnt(4) (4 gl16/unit, 2 units in flight), R4 XCD bid mapping.
__launch_bounds__(TPB1, 4)
__global__ void knn_phase1(const __hip_bfloat16* __restrict__ Qbf,
                           const __hip_bfloat16* __restrict__ Mbf,
                           const float* __restrict__ m2,
                           float* __restrict__ keyws,
                           unsigned short* __restrict__ idxws) {
    __shared__ alignas(16) __bf16 As[2][BM][BK];   // mem tiles   (2 x 8 KB)
    __shared__ alignas(16) __bf16 Bs[2][BN][BK];   // query tiles (2 x 8 KB)
    __shared__ float m2s[SLICE];                   // 4 KB

    const int t    = threadIdx.x;
    const int lane = t & 63;
    const int wave = t >> 6;
    const int wb   = wave >> 1;     // 0..1 : 64-row (mem) band
    const int cb   = wave & 1;      // 0..1 : 64-col (query) band
    const int g4   = lane >> 4;     // 0..3
    const int l16  = lane & 15;

    // R4-style bid mapping: XCD x owns q-chunks {x, 8+x, ...} (L2-hot); slices stream
    const int bid  = blockIdx.x;
    const int qlow = bid & 7;
    const int rest = bid >> 3;
    const int sp   = rest & 15;        // 0..15
    const int qhi  = rest >> 4;        // 0..7
    const int qc   = qhi * 8 + qlow;   // 0..63
    const int q0   = qc * BN;
    const int mbase = sp * SLICE;

    // prologue: m2 slice -> LDS (reg-staged; vmcnt drained BEFORE any gl16)
    {
        float m2r[SLICE / TPB1];
#pragma unroll
        for (int i = 0; i < SLICE / TPB1; ++i) m2r[i] = m2[mbase + t + i * TPB1];
        asm volatile("s_waitcnt vmcnt(0)" ::: "memory");
#pragma unroll
        for (int i = 0; i < SLICE / TPB1; ++i) m2s[t + i * TPB1] = m2r[i];
        __syncthreads();
    }

    // per-(thread, col jf) sorted top-5 (key ascending)
    float    tk[4][5];
    unsigned ti[4][5];
#pragma unroll
    for (int j = 0; j < 4; ++j)
#pragma unroll
        for (int r = 0; r < 5; ++r) { tk[j][r] = 3.4e38f; ti[j][r] = 0u; }

    // staging: thread t -> LDS physical (row = t>>2, chunk = t&3);
    // fetch global logical chunk lc = (t&3) ^ ((row>>1)&3)  (involution)
    const int srow = t >> 2;                                 // 0..63
    const int scol = (((t & 3) ^ ((srow >> 1) & 3)) << 3);   // pre-swizzled elems
    // read-side swizzled chunk for logical chunk g4 at rows 16m+l16:
    const int koff = ((g4 ^ ((l16 >> 1) & 3)) << 3);         // elements

    f32x4_t acc[4][4];
#pragma unroll
    for (int i = 0; i < 4; ++i)
#pragma unroll
        for (int j = 0; j < 4; ++j) acc[i][j] = {0.f, 0.f, 0.f, 0.f};

    // ---- stage helper (4 x gl16 per unit: 2 sweeps of A(128x32), 2 of B(128x32)) ----
    auto stage = [&](int s, int buf) {
        const int tl  = s >> 5;
        const int kk0 = (s & 31) * BK;
        const int rr0 = mbase + tl * BM;
        const __hip_bfloat16* ga = Mbf + (size_t)(rr0 + srow) * DIM + kk0 + scol;
        const __hip_bfloat16* gb = Qbf + (size_t)(q0 + srow) * DIM + kk0 + scol;
        char* la = (char*)&As[buf][0][0] + t * 16;
        char* lb = (char*)&Bs[buf][0][0] + t * 16;
        gl16(ga,            la);
        gl16(ga + 64 * DIM, la + 4096);   // rows +64: (row>>1)&3 unchanged
        gl16(gb,            lb);
        gl16(gb + 64 * DIM, lb + 4096);
    };

    // prologue: 2 units in flight (8 loads)
    stage(0, 0);
    stage(1, 1);

#pragma unroll 1
    for (int s = 0; s < UNITS; ++s) {
        const int cur = s & 1;

        if (s == UNITS - 1) asm volatile("s_waitcnt vmcnt(0)" ::: "memory");
        else                asm volatile("s_waitcnt vmcnt(4)" ::: "memory");
        __builtin_amdgcn_s_barrier();

        __builtin_amdgcn_s_setprio(1);
        {
            bf16x8_t bfr[4];
#pragma unroll
            for (int jf = 0; jf < 4; ++jf) {
                const int bc = cb * 64 + jf * 16 + l16;
                bfr[jf] = *reinterpret_cast<const bf16x8_t*>(&Bs[cur][bc][koff]);
            }
#pragma unroll
            for (int rf = 0; rf < 4; ++rf) {
                const int ar = wb * 64 + rf * 16 + l16;
                const bf16x8_t a = *reinterpret_cast<const bf16x8_t*>(&As[cur][ar][koff]);
                acc[rf][0] = __builtin_amdgcn_mfma_f32_16x16x32_bf16(a, bfr[0], acc[rf][0], 0, 0, 0);
                acc[rf][1] = __builtin_amdgcn_mfma_f32_16x16x32_bf16(a, bfr[1], acc[rf][1], 0, 0, 0);
                acc[rf][2] = __builtin_amdgcn_mfma_f32_16x16x32_bf16(a, bfr[2], acc[rf][2], 0, 0, 0);
                acc[rf][3] = __builtin_amdgcn_mfma_f32_16x16x32_bf16(a, bfr[3], acc[rf][3], 0, 0, 0);
            }
        }
        __builtin_amdgcn_s_setprio(0);

        asm volatile("s_waitcnt lgkmcnt(0)" ::: "memory");
        __builtin_amdgcn_s_barrier();

        if (s + 2 < UNITS) stage(s + 2, cur);   // refill the pipeline (no wait)

        if ((s & 31) == 31) {
            // tile complete: fold acc into per-col top-5 (LDS m2s + registers only)
            const int tl = s >> 5;
            const int r0 = mbase + tl * BM;
#pragma unroll
            for (int rf = 0; rf < 4; ++rf) {
#pragma unroll
                for (int rg = 0; rg < 4; ++rg) {
                    const int lr = wb * 64 + rf * 16 + g4 * 4 + rg;  // local mem row
                    const float mm = m2s[tl * BM + lr];              // LDS broadcast
                    const unsigned gidx = (unsigned)(r0 + lr);
#pragma unroll
                    for (int j = 0; j < 4; ++j) {
                        const float key = fmaf(-2.0f, acc[rf][j][rg], mm);
                        if (key < tk[j][4]) {
                            tk[j][4] = key; ti[j][4] = gidx;
#pragma unroll
                            for (int ss = 3; ss >= 0; --ss) {
                                const bool sw = tk[j][ss] > tk[j][ss + 1];
                                const float    fa = tk[j][ss], fb = tk[j][ss + 1];
                                const unsigned ia = ti[j][ss], ib = ti[j][ss + 1];
                                tk[j][ss] = sw ? fb : fa; tk[j][ss + 1] = sw ? fa : fb;
                                ti[j][ss] = sw ? ib : ia; ti[j][ss + 1] = sw ? ia : ib;
                            }
                        }
                    }
                }
            }
#pragma unroll
            for (int i = 0; i < 4; ++i)
#pragma unroll
                for (int j = 0; j < 4; ++j) acc[i][j] = {0.f, 0.f, 0.f, 0.f};
        }
    }

    // write candidates: per col 8 streams (wb,g4) x top5; slot = sp*40 + (wb*4+g4)*5 + r
#pragma unroll
    for (int j = 0; j < 4; ++j) {
        const int col = cb * 64 + j * 16 + l16;
        const size_t base = (size_t)(q0 + col) * CPQ + sp * 40 + (wb * 4 + g4) * 5;
#pragma unroll
        for (int r = 0; r < 5; ++r) {
            keyws[base + r] = tk[j][r];
            idxws[base + r] = (unsigned short)ti[j][r];
        }
    }
}

// ---------------- fast phase 2: merge 640 -> 16, exact f64 rescore, formula ----------------
__global__ void knn_phase2(const float* __restrict__ query,
                           const float* __restrict__ mem,
                           const float* __restrict__ nsb,
                           const float* __restrict__ keyws,
                           const unsigned short* __restrict__ idxws,
                           float* __restrict__ out) {
    const int wv   = threadIdx.x >> 6;
    const int lane = threadIdx.x & 63;
    const int row  = blockIdx.x * 4 + wv;

    __shared__ int   sel[4][16];
    __shared__ float dsel[4][16];

    float    k[10];
    unsigned id[10];
    const size_t cb = (size_t)row * CPQ;
#pragma unroll
    for (int r = 0; r < 10; ++r) {
        k[r]  = keyws[cb + r * 64 + lane];
        id[r] = (unsigned)idxws[cb + r * 64 + lane];
    }

    for (int rr = 0; rr < 16; ++rr) {
        float lm = k[0];
#pragma unroll
        for (int r = 1; r < 10; ++r) lm = fminf(lm, k[r]);
        float m = lm;
#pragma unroll
        for (int off = 32; off > 0; off >>= 1) m = fminf(m, __shfl_xor(m, off));
        const unsigned long long bal = __ballot(lm == m);
        const bool win = (lane == (int)(__ffsll((long long)bal) - 1));
        unsigned sid = 0; bool done = false;
#pragma unroll
        for (int r = 0; r < 10; ++r) {
            const bool c = win && !done && (k[r] == m);
            sid  = c ? id[r] : sid;
            k[r] = c ? 3.4e38f : k[r];
            done = done || c;
        }
        if (win) sel[wv][rr] = (int)sid;
    }
    __syncthreads();

    // exact rescore: 4 lanes per candidate, f64 accumulation of (q-m)^2
    const int c = lane >> 2, sub = lane & 3;
    const int mi = sel[wv][c];
    const float4* qp = reinterpret_cast<const float4*>(query + (size_t)row * DIM) + sub * 64;
    const float4* mp = reinterpret_cast<const float4*>(mem + (size_t)mi * DIM) + sub * 64;
    double acc = 0.0;
#pragma unroll 4
    for (int i = 0; i < 64; ++i) {
        const float4 q4 = qp[i];
        const float4 m4 = mp[i];
        const double d0 = (double)q4.x - (double)m4.x;
        const double d1 = (double)q4.y - (double)m4.y;
        const double d2 = (double)q4.z - (double)m4.z;
        const double d3 = (double)q4.w - (double)m4.w;
        acc += d0 * d0 + d1 * d1 + d2 * d2 + d3 * d3;
    }
    acc += __shfl_xor(acc, 1);
    acc += __shfl_xor(acc, 2);
    if (sub == 0) dsel[wv][c] = (float)sqrt(fmax(acc, 1e-12));
    __syncthreads();

    if (lane == 0) {
        float dv[16]; int di[16];
#pragma unroll
        for (int i = 0; i < 16; ++i) { dv[i] = dsel[wv][i]; di[i] = sel[wv][i]; }
        float kd[KNN]; int ki[KNN];
#pragma unroll
        for (int r = 0; r < KNN; ++r) {
            float bv = 3.4e38f; int bi = 0x7fffffff; int bp = -1;
#pragma unroll
            for (int i = 0; i < 16; ++i) {
                const bool better = (dv[i] < bv) || (dv[i] == bv && di[i] < bi);
                if (better) { bv = dv[i]; bi = di[i]; bp = i; }
            }
            kd[r] = bv; ki[r] = bi;
#pragma unroll
            for (int i = 0; i < 16; ++i) if (i == bp) dv[i] = 3.4e38f;
        }
        double dmin = (double)kd[0];
#pragma unroll
        for (int r = 1; r < KNN; ++r) dmin = fmin(dmin, (double)kd[r]);
        double w[KNN], se = 0.0, wd = 0.0, sd = 0.0, sc = 0.0;
#pragma unroll
        for (int r = 0; r < KNN; ++r) {
            w[r] = exp(-((double)kd[r] - dmin));
            se += w[r];
            sd += (double)kd[r];
            sc += (double)nsb[ki[r]];
        }
#pragma unroll
        for (int r = 0; r < KNN; ++r) wd += w[r] * (double)kd[r];
        wd /= se;
        sc /= (double)KNN;
        const double nd   = wd / fmax(sc, 1e-6);
        const double mean = sd / (double)KNN;
        double var = 0.0;
#pragma unroll
        for (int r = 0; r < KNN; ++r) { const double dd = (double)kd[r] - mean; var += dd * dd; }
        var /= (double)KNN;
        const double cons = sqrt(var) / fmax(mean, 1e-6);
        out[row] = (float)(nd * (1.0 + 0.5 * cons));
    }
}

// ================= fallback path (round-1, proven; used if ws too small) =================
typedef float f32x4fb_t __attribute__((ext_vector_type(4)));

__global__ void fb_m2_kernel(const float* __restrict__ mem, float* __restrict__ m2) {
    const int row  = blockIdx.x * 4 + (threadIdx.x >> 6);
    const int lane = threadIdx.x & 63;
    const float4* p = reinterpret_cast<const float4*>(mem + (size_t)row * DIM) + lane;
    float s = 0.f;
#pragma unroll
    for (int i = 0; i < 4; ++i) {
        const float4 v = p[i * 64];
        s += v.x * v.x + v.y * v.y + v.z * v.z + v.w * v.w;
    }
#pragma unroll
    for (int off = 32; off > 0; off >>= 1) s += __shfl_down(s, off);
    if (lane == 0) m2[row] = s;
}

__launch_bounds__(512, 1)
__global__ void fb_knn_phase1(const float* __restrict__ query,
                              const float* __restrict__ mem,
                              const float* __restrict__ m2,
                              float* __restrict__ wkey,
                              int* __restrict__ widx) {
    __shared__ alignas(16) __bf16 Qs[128][72];
    __shared__ alignas(16) __bf16 Ms[128][72];
    __shared__ float D2[128][129];
    __shared__ float m2s[128];

    const int t    = threadIdx.x;
    const int lane = t & 63;
    const int wave = t >> 6;
    const int wr   = wave >> 1;
    const int wc   = wave & 1;

    const int mb    = blockIdx.x & 63;
    const int sp    = blockIdx.x >> 6;
    const int q0    = mb * 128;
    const int mbase = sp * 4096;

    const int srow = t & 127;
    const int sseg = t >> 7;
    const int str = t >> 2;
    const int stc = (t & 3) * 16;

    float topv[8]; int topi[8];
#pragma unroll
    for (int i = 0; i < 8; ++i) { topv[i] = 3.4e38f; topi[i] = 0; }
    float curmax = 3.4e38f;
    const f32x4fb_t zero = {0.f, 0.f, 0.f, 0.f};

    for (int tile = 0; tile < 32; ++tile) {
        const int c0 = mbase + tile * 128;
        if (t < 128) m2s[t] = m2[c0 + t];
        f32x4fb_t acc[2][4];
#pragma unroll
        for (int i = 0; i < 2; ++i)
#pragma unroll
            for (int j = 0; j < 4; ++j) acc[i][j] = zero;

        for (int k0 = 0; k0 < DIM; k0 += 64) {
            {
                const float4* qp = reinterpret_cast<const float4*>(query + (size_t)(q0 + str) * DIM + k0 + stc);
                const float4 a0 = qp[0], a1 = qp[1], a2 = qp[2], a3 = qp[3];
                const float4* mp = reinterpret_cast<const float4*>(mem + (size_t)(c0 + str) * DIM + k0 + stc);
                const float4 b0 = mp[0], b1 = mp[1], b2 = mp[2], b3 = mp[3];
                bf16x8_t qa, qb, ma, mbv;
                qa[0] = (__bf16)a0.x; qa[1] = (__bf16)a0.y; qa[2] = (__bf16)a0.z; qa[3] = (__bf16)a0.w;
                qa[4] = (__bf16)a1.x; qa[5] = (__bf16)a1.y; qa[6] = (__bf16)a1.z; qa[7] = (__bf16)a1.w;
                qb[0] = (__bf16)a2.x; qb[1] = (__bf16)a2.y; qb[2] = (__bf16)a2.z; qb[3] = (__bf16)a2.w;
                qb[4] = (__bf16)a3.x; qb[5] = (__bf16)a3.y; qb[6] = (__bf16)a3.z; qb[7] = (__bf16)a3.w;
                ma[0] = (__bf16)b0.x; ma[1] = (__bf16)b0.y; ma[2] = (__bf16)b0.z; ma[3] = (__bf16)b0.w;
                ma[4] = (__bf16)b1.x; ma[5] = (__bf16)b1.y; ma[6] = (__bf16)b1.z; ma[7] = (__bf16)b1.w;
                mbv[0] = (__bf16)b2.x; mbv[1] = (__bf16)b2.y; mbv[2] = (__bf16)b2.z; mbv[3] = (__bf16)b2.w;
                mbv[4] = (__bf16)b3.x; mbv[5] = (__bf16)b3.y; mbv[6] = (__bf16)b3.z; mbv[7] = (__bf16)b3.w;
                *reinterpret_cast<bf16x8_t*>(&Qs[str][stc])     = qa;
                *reinterpret_cast<bf16x8_t*>(&Qs[str][stc + 8]) = qb;
                *reinterpret_cast<bf16x8_t*>(&Ms[str][stc])     = ma;
                *reinterpret_cast<bf16x8_t*>(&Ms[str][stc + 8]) = mbv;
            }
            __syncthreads();
#pragma unroll
            for (int kk = 0; kk < 64; kk += 32) {
                const int koff = kk + ((lane >> 4) << 3);
                const int ar   = wr * 32 + (lane & 15);
                const bf16x8_t a0 = *reinterpret_cast<const bf16x8_t*>(&Qs[ar][koff]);
                const bf16x8_t a1 = *reinterpret_cast<const bf16x8_t*>(&Qs[ar + 16][koff]);
                const int bc = wc * 64 + (lane & 15);
                const bf16x8_t b0 = *reinterpret_cast<const bf16x8_t*>(&Ms[bc][koff]);
                const bf16x8_t b1 = *reinterpret_cast<const bf16x8_t*>(&Ms[bc + 16][koff]);
                const bf16x8_t b2 = *reinterpret_cast<const bf16x8_t*>(&Ms[bc + 32][koff]);
                const bf16x8_t b3 = *reinterpret_cast<const bf16x8_t*>(&Ms[bc + 48][koff]);
                acc[0][0] = __builtin_amdgcn_mfma_f32_16x16x32_bf16(a0, b0, acc[0][0], 0, 0, 0);
                acc[0][1] = __builtin_amdgcn_mfma_f32_16x16x32_bf16(a0, b1, acc[0][1], 0, 0, 0);
                acc[0][2] = __builtin_amdgcn_mfma_f32_16x16x32_bf16(a0, b2, acc[0][2], 0, 0, 0);
                acc[0][3] = __builtin_amdgcn_mfma_f32_16x16x32_bf16(a0, b3, acc[0][3], 0, 0, 0);
                acc[1][0] = __builtin_amdgcn_mfma_f32_16x16x32_bf16(a1, b0, acc[1][0], 0, 0, 0);
                acc[1][1] = __builtin_amdgcn_mfma_f32_16x16x32_bf16(a1, b1, acc[1][1], 0, 0, 0);
                acc[1][2] = __builtin_amdgcn_mfma_f32_16x16x32_bf16(a1, b2, acc[1][2], 0, 0, 0);
                acc[1][3] = __builtin_amdgcn_mfma_f32_16x16x32_bf16(a1, b3, acc[1][3], 0, 0, 0);
            }
            __syncthreads();
        }
#pragma unroll
        for (int i = 0; i < 2; ++i) {
            const int r0 = wr * 32 + i * 16 + ((lane >> 4) << 2);
#pragma unroll
            for (int j = 0; j < 4; ++j) {
                const int cc = wc * 64 + j * 16 + (lane & 15);
                const float mm = m2s[cc];
#pragma unroll
                for (int rg = 0; rg < 4; ++rg)
                    D2[r0 + rg][cc] = mm - 2.0f * acc[i][j][rg];
            }
        }
        __syncthreads();
        {
            const int gbase = c0 + sseg * 32;
#pragma unroll 8
            for (int cc = 0; cc < 32; ++cc) {
                const float key = D2[srow][sseg * 32 + cc];
                if (key < curmax) {
                    bool done = false;
#pragma unroll
                    for (int i = 0; i < 8; ++i) {
                        if (!done && topv[i] == curmax) {
                            topv[i] = key; topi[i] = gbase + cc; done = true;
                        }
                    }
                    curmax = topv[0];
#pragma unroll
                    for (int i = 1; i < 8; ++i) curmax = fmaxf(curmax, topv[i]);
                }
            }
        }
        __syncthreads();
    }
    const size_t base = ((size_t)(q0 + srow) * 4 + sp) * 32 + (size_t)sseg * 8;
#pragma unroll
    for (int j = 0; j < 8; ++j) { wkey[base + j] = topv[j]; widx[base + j] = topi[j]; }
}

__global__ void fb_knn_phase2(const float* __restrict__ query,
                              const float* __restrict__ mem,
                              const float* __restrict__ nsb,
                              const float* __restrict__ wkey,
                              const int* __restrict__ widx,
                              float* __restrict__ out) {
    const int wv   = threadIdx.x >> 6;
    const int lane = threadIdx.x & 63;
    const int row  = blockIdx.x * 4 + wv;
    __shared__ int   sel[4][16];
    __shared__ float dsel[4][16];

    const size_t cb = (size_t)row * 128;
    float k0 = wkey[cb + lane];
    float k1 = wkey[cb + 64 + lane];
    const int i0 = widx[cb + lane];
    const int i1 = widx[cb + 64 + lane];

    for (int r = 0; r < 16; ++r) {
        float m = fminf(k0, k1);
#pragma unroll
        for (int off = 32; off > 0; off >>= 1) m = fminf(m, __shfl_xor(m, off));
        const unsigned long long b0 = __ballot(k0 == m);
        const unsigned long long b1 = __ballot(k1 == m);
        if (b0) {
            if (lane == __ffsll(b0) - 1) { sel[wv][r] = i0; k0 = 3.4e38f; }
        } else {
            if (lane == __ffsll(b1) - 1) { sel[wv][r] = i1; k1 = 3.4e38f; }
        }
    }
    __syncthreads();

    const int c = lane >> 2, sub = lane & 3;
    const int mi = sel[wv][c];
    const float4* qp = reinterpret_cast<const float4*>(query + (size_t)row * DIM) + sub * 64;
    const float4* mp = reinterpret_cast<const float4*>(mem + (size_t)mi * DIM) + sub * 64;
    double acc = 0.0;
#pragma unroll 4
    for (int i = 0; i < 64; ++i) {
        const float4 q4 = qp[i];
        const float4 m4 = mp[i];
        const double d0 = (double)q4.x - (double)m4.x;
        const double d1 = (double)q4.y - (double)m4.y;
        const double d2 = (double)q4.z - (double)m4.z;
        const double d3 = (double)q4.w - (double)m4.w;
        acc += d0 * d0 + d1 * d1 + d2 * d2 + d3 * d3;
    }
    acc += __shfl_xor(acc, 1);
    acc += __shfl_xor(acc, 2);
    if (sub == 0) dsel[wv][c] = (float)sqrt(fmax(acc, 1e-12));
    __syncthreads();

    if (lane == 0) {
        float dv[16]; int di[16];
#pragma unroll
        for (int i = 0; i < 16; ++i) { dv[i] = dsel[wv][i]; di[i] = sel[wv][i]; }
        float kd[KNN]; int ki[KNN];
#pragma unroll
        for (int r = 0; r < KNN; ++r) {
            float bv = 3.4e38f; int bi = 0x7fffffff; int bp = -1;
#pragma unroll
            for (int i = 0; i < 16; ++i) {
                const bool better = (dv[i] < bv) || (dv[i] == bv && di[i] < bi);
                if (better) { bv = dv[i]; bi = di[i]; bp = i; }
            }
            kd[r] = bv; ki[r] = bi;
#pragma unroll
            for (int i = 0; i < 16; ++i) if (i == bp) dv[i] = 3.4e38f;
        }
        double dmin = (double)kd[0];
#pragma unroll
        for (int r = 1; r < KNN; ++r) dmin = fmin(dmin, (double)kd[r]);
        double w[KNN], se = 0.0, wd = 0.0, sd = 0.0, sc = 0.0;
#pragma unroll
        for (int r = 0; r < KNN; ++r) {
            w[r] = exp(-((double)kd[r] - dmin));
            se += w[r];
            sd += (double)kd[r];
            sc += (double)nsb[ki[r]];
        }
#pragma unroll
        for (int r = 0; r < KNN; ++r) wd += w[r] * (double)kd[r];
        wd /= se;
        sc /= (double)KNN;
        const double nd   = wd / fmax(sc, 1e-6);
        const double mean = sd / (double)KNN;
        double var = 0.0;
#pragma unroll
        for (int r = 0; r < KNN; ++r) { const double dd = (double)kd[r] - mean; var += dd * dd; }
        var /= (double)KNN;
        const double cons = sqrt(var) / fmax(mean, 1e-6);
        out[row] = (float)(nd * (1.0 + 0.5 * cons));
    }
}

extern "C" void kernel_launch(void* const* d_in, const int* in_sizes, int n_in,
                              void* d_out, int out_size, void* d_ws, size_t ws_size,
                              hipStream_t stream) {
    const float* query = (const float*)d_in[0];
    const float* mem   = (const float*)d_in[1];
    const float* nsb   = (const float*)d_in[2];
    float* out = (float*)d_out;
    char* ws = (char*)d_ws;

    const size_t offQ   = 0;
    const size_t offM   = offQ + (size_t)NQ * DIM * 2;      // 16 MB
    const size_t offm2  = offM + (size_t)NM * DIM * 2;      // +32 MB
    const size_t offkey = offm2 + (size_t)NM * 4;           // +64 KB
    const size_t offidx = offkey + (size_t)NQ * CPQ * 4;    // +20 MB
    const size_t need   = offidx + (size_t)NQ * CPQ * 2;    // +10 MB (~78 MB)

    if (ws_size >= need) {
        __hip_bfloat16* Qbf = (__hip_bfloat16*)(ws + offQ);
        __hip_bfloat16* Mbf = (__hip_bfloat16*)(ws + offM);
        float*          m2  = (float*)(ws + offm2);
        float*          key = (float*)(ws + offkey);
        unsigned short* idx = (unsigned short*)(ws + offidx);

        hipLaunchKernelGGL(cvt_bf16_kernel, dim3(NQ * DIM / 8 / 256), dim3(256), 0, stream,
                           query, Qbf, NQ * DIM / 8);
        hipLaunchKernelGGL(cvt_m2_kernel, dim3(NM / 4), dim3(256), 0, stream, mem, Mbf, m2);
        hipLaunchKernelGGL(knn_phase1, dim3((NQ / BN) * SPLITS), dim3(TPB1), 0, stream,
                           Qbf, Mbf, m2, key, idx);
        hipLaunchKernelGGL(knn_phase2, dim3(NQ / 4), dim3(256), 0, stream,
                           query, mem, nsb, key, idx, out);
    } else {
        float* wkey = (float*)ws;                              // 4 MB
        int*   widx = (int*)(ws + (size_t)NQ * 128 * 4);       // 4 MB
        float* m2   = (float*)(ws + (size_t)NQ * 128 * 8);     // 64 KB
        hipLaunchKernelGGL(fb_m2_kernel, dim3(NM / 4), dim3(256), 0, stream, mem, m2);
        hipLaunchKernelGGL(fb_knn_phase1, dim3((NQ / 128) * 4), dim3(512), 0, stream,
                           query, mem, m2, wkey, widx);
        hipLaunchKernelGGL(fb_knn_phase2, dim3(NQ / 4), dim3(256), 0, stream,
                           query, mem, nsb, wkey, widx, out);
    }
}

// Round 10
// 490.505 us; speedup vs baseline: 1.9827x; 1.9827x over previous
//
#include <hip/hip_runtime.h>
#include <hip/hip_bf16.h>
#include <math.h>

#define NQ   8192
#define NM   16384
#define DIM  1024
#define KNN  5

// ---------------- fast path config (R4 geometry — measured optimum) ----------------
#define SPLITS 8
#define SLICE  (NM / SPLITS)      // 2048
#define TILEM  128                // mem rows per tile
#define TILES  (SLICE / TILEM)    // 16
#define BK     64
#define UNITS  (TILES * (DIM / BK))  // 256 stage units per block
#define TPB1   512
#define CPQ    (SPLITS * 16 * 5)  // 640 candidates per query

typedef float  f32x4_t  __attribute__((ext_vector_type(4)));
typedef __bf16 bf16x8_t __attribute__((ext_vector_type(8)));

typedef __attribute__((address_space(1))) unsigned int gu32_t;
typedef __attribute__((address_space(3))) unsigned int lu32_t;

__device__ __forceinline__ void gl16(const void* g, void* l) {
    __builtin_amdgcn_global_load_lds((gu32_t*)g, (lu32_t*)l, 16, 0, 0);
}

// ---------------- fast: mem f32 -> bf16 convert + squared norms (fused) ----------------
__global__ void cvt_m2_kernel(const float* __restrict__ mem,
                              __hip_bfloat16* __restrict__ out,
                              float* __restrict__ m2) {
    const int row  = blockIdx.x * 4 + (threadIdx.x >> 6);
    const int lane = threadIdx.x & 63;
    const float4* p = reinterpret_cast<const float4*>(mem + (size_t)row * DIM + lane * 16);
    float s = 0.f;
#pragma unroll
    for (int h = 0; h < 2; ++h) {
        const float4 a = p[2 * h];
        const float4 b = p[2 * h + 1];
        bf16x8_t v;
        v[0] = (__bf16)a.x; v[1] = (__bf16)a.y; v[2] = (__bf16)a.z; v[3] = (__bf16)a.w;
        v[4] = (__bf16)b.x; v[5] = (__bf16)b.y; v[6] = (__bf16)b.z; v[7] = (__bf16)b.w;
        reinterpret_cast<bf16x8_t*>(out + (size_t)row * DIM + lane * 16)[h] = v;
        s += a.x * a.x + a.y * a.y + a.z * a.z + a.w * a.w;
        s += b.x * b.x + b.y * b.y + b.z * b.z + b.w * b.w;
    }
#pragma unroll
    for (int off = 32; off > 0; off >>= 1) s += __shfl_down(s, off);
    if (lane == 0) m2[row] = s;
}

// ---------------- fast: query f32 -> bf16 convert ----------------
__global__ void cvt_bf16_kernel(const float* __restrict__ in,
                                __hip_bfloat16* __restrict__ out, int n8) {
    const int i = blockIdx.x * blockDim.x + threadIdx.x;
    if (i >= n8) return;
    const float4 a = reinterpret_cast<const float4*>(in)[2 * i];
    const float4 b = reinterpret_cast<const float4*>(in)[2 * i + 1];
    bf16x8_t v;
    v[0] = (__bf16)a.x; v[1] = (__bf16)a.y; v[2] = (__bf16)a.z; v[3] = (__bf16)a.w;
    v[4] = (__bf16)b.x; v[5] = (__bf16)b.y; v[6] = (__bf16)b.z; v[7] = (__bf16)b.w;
    reinterpret_cast<bf16x8_t*>(out)[i] = v;
}

// ---------------- fast phase 1: transposed GEMM + in-register top-5 (R4 verbatim) ----
// Measured optimum across R4-R9 sweep: 16 waves/CU (launch_bounds(512,4) -> 2 blocks
// x 8 waves), acc[2][4] (32 AGPR + 64 VGPR = 96 <= 128 unified budget, no spill),
// BK=64 dbuf (72 KB LDS), XOR swizzle chunk^=row&7 both-sides (0 conflicts),
// counted vmcnt(4) (4 gl16/unit, 2 units in flight), R4 XCD bid mapping (8 q-chunks
// per XCD L2-hot). Register-budget law (R7/R9): total VGPR+AGPR <= 512/waves_per_EU;
// 64x64 wave tiles + 40-reg top-5 state cannot fit at 4 waves/EU -> 0.75 reads/MFMA
// at 16 waves beats 0.5 at 8 waves (356 vs 498 us).
__launch_bounds__(TPB1, 4)
__global__ void knn_phase1(const __hip_bfloat16* __restrict__ Qbf,
                           const __hip_bfloat16* __restrict__ Mbf,
                           const float* __restrict__ m2,
                           float* __restrict__ keyws,
                           unsigned short* __restrict__ idxws) {
    __shared__ alignas(16) __bf16 As[2][TILEM][BK];  // mem tiles   (2 x 16 KB)
    __shared__ alignas(16) __bf16 Bs[2][128][BK];    // query tiles (2 x 16 KB)
    __shared__ float m2s[SLICE];                     // 8 KB

    const int t    = threadIdx.x;
    const int lane = t & 63;
    const int wave = t >> 6;
    const int wr   = wave >> 1;     // 0..3 : 32-row (mem) band
    const int wc   = wave & 1;      // 0..1 : 64-col (query) band
    const int g4   = lane >> 4;     // 0..3
    const int l16  = lane & 15;

    // XCD mapping: XCD x owns q-chunks {x, 8+x, ...} (Q L2-hot), all splits per chunk
    const int bid  = blockIdx.x;
    const int qlow = bid & 7;
    const int rest = bid >> 3;
    const int sp   = rest & 7;
    const int qhi  = rest >> 3;
    const int qc   = qhi * 8 + qlow;   // 0..63
    const int q0   = qc * 128;
    const int mbase = sp * SLICE;

    // stage m2 slice into LDS (loads drain via compiler waitcnt before ds_write;
    // vmcnt ledger clean before first gl16)
#pragma unroll
    for (int i = 0; i < SLICE / TPB1; ++i) m2s[t + i * TPB1] = m2[mbase + t + i * TPB1];

    // per-(thread, col j) sorted top-5 (key ascending)
    float    tk[4][5];
    unsigned ti[4][5];
#pragma unroll
    for (int j = 0; j < 4; ++j)
#pragma unroll
        for (int r = 0; r < 5; ++r) { tk[j][r] = 3.4e38f; ti[j][r] = 0u; }

    // staging: thread t -> LDS physical (row = t>>3, chunk = t&7);
    // fetch global logical chunk lc = (t&7) ^ (row&7)  (involution)
    const int srow = t >> 3;                          // 0..63
    const int scol = (((t & 7) ^ (srow & 7)) << 3);   // pre-swizzled element offset
    const int rxa  = l16 & 7;                         // row&7 for all frag rows read

    f32x4_t acc[2][4];
#pragma unroll
    for (int i = 0; i < 2; ++i)
#pragma unroll
        for (int j = 0; j < 4; ++j) acc[i][j] = {0.f, 0.f, 0.f, 0.f};

    // ---- stage helper (4 x gl16 per unit) ----
    auto stage = [&](int s, int buf) {
        const int tl  = s >> 4;
        const int kk0 = (s & 15) * BK;
        const int rr0 = mbase + tl * TILEM;
        const __hip_bfloat16* ga = Mbf + (size_t)(rr0 + srow) * DIM + kk0 + scol;
        const __hip_bfloat16* gb = Qbf + (size_t)(q0 + srow) * DIM + kk0 + scol;
        char* la = (char*)&As[buf][0][0] + t * 16;
        char* lb = (char*)&Bs[buf][0][0] + t * 16;
        gl16(ga,            la);
        gl16(ga + 64 * DIM, la + 8192);   // rows +64: (row&7) unchanged
        gl16(gb,            lb);
        gl16(gb + 64 * DIM, lb + 8192);
    };

    // prologue: 2 units in flight (8 loads)
    stage(0, 0);
    stage(1, 1);

#pragma unroll 1
    for (int s = 0; s < UNITS; ++s) {
        const int cur = s & 1;

        if (s == UNITS - 1) asm volatile("s_waitcnt vmcnt(0)" ::: "memory");
        else                asm volatile("s_waitcnt vmcnt(4)" ::: "memory");
        __builtin_amdgcn_s_barrier();

        __builtin_amdgcn_s_setprio(1);
#pragma unroll
        for (int kk = 0; kk < BK; kk += 32) {
            const int ch   = (kk >> 3) + g4;            // logical chunk 0..7
            const int koff = ((ch ^ rxa) << 3);         // swizzled read offset
            const int ar   = wr * 32 + l16;
            const int bc   = wc * 64 + l16;
            const bf16x8_t a0 = *reinterpret_cast<const bf16x8_t*>(&As[cur][ar][koff]);
            const bf16x8_t a1 = *reinterpret_cast<const bf16x8_t*>(&As[cur][ar + 16][koff]);
            const bf16x8_t b0 = *reinterpret_cast<const bf16x8_t*>(&Bs[cur][bc][koff]);
            const bf16x8_t b1 = *reinterpret_cast<const bf16x8_t*>(&Bs[cur][bc + 16][koff]);
            const bf16x8_t b2 = *reinterpret_cast<const bf16x8_t*>(&Bs[cur][bc + 32][koff]);
            const bf16x8_t b3 = *reinterpret_cast<const bf16x8_t*>(&Bs[cur][bc + 48][koff]);
            acc[0][0] = __builtin_amdgcn_mfma_f32_16x16x32_bf16(a0, b0, acc[0][0], 0, 0, 0);
            acc[0][1] = __builtin_amdgcn_mfma_f32_16x16x32_bf16(a0, b1, acc[0][1], 0, 0, 0);
            acc[0][2] = __builtin_amdgcn_mfma_f32_16x16x32_bf16(a0, b2, acc[0][2], 0, 0, 0);
            acc[0][3] = __builtin_amdgcn_mfma_f32_16x16x32_bf16(a0, b3, acc[0][3], 0, 0, 0);
            acc[1][0] = __builtin_amdgcn_mfma_f32_16x16x32_bf16(a1, b0, acc[1][0], 0, 0, 0);
            acc[1][1] = __builtin_amdgcn_mfma_f32_16x16x32_bf16(a1, b1, acc[1][1], 0, 0, 0);
            acc[1][2] = __builtin_amdgcn_mfma_f32_16x16x32_bf16(a1, b2, acc[1][2], 0, 0, 0);
            acc[1][3] = __builtin_amdgcn_mfma_f32_16x16x32_bf16(a1, b3, acc[1][3], 0, 0, 0);
        }
        __builtin_amdgcn_s_setprio(0);

        asm volatile("s_waitcnt lgkmcnt(0)" ::: "memory");
        __builtin_amdgcn_s_barrier();

        if (s + 2 < UNITS) stage(s + 2, cur);   // refill the pipeline (no wait)

        if ((s & 15) == 15) {
            // tile complete: fold acc into per-col top-5 (LDS m2s + registers only)
            const int tl = s >> 4;
            const int r0 = mbase + tl * TILEM;
#pragma unroll
            for (int i = 0; i < 2; ++i) {
#pragma unroll
                for (int rg = 0; rg < 4; ++rg) {
                    const int lr = wr * 32 + i * 16 + g4 * 4 + rg;  // local mem row
                    const float mm = m2s[tl * TILEM + lr];          // LDS broadcast
                    const unsigned gidx = (unsigned)(r0 + lr);
#pragma unroll
                    for (int j = 0; j < 4; ++j) {
                        const float key = fmaf(-2.0f, acc[i][j][rg], mm);
                        if (key < tk[j][4]) {
                            tk[j][4] = key; ti[j][4] = gidx;
#pragma unroll
                            for (int ss = 3; ss >= 0; --ss) {
                                const bool sw = tk[j][ss] > tk[j][ss + 1];
                                const float    fa = tk[j][ss], fb = tk[j][ss + 1];
                                const unsigned ia = ti[j][ss], ib = ti[j][ss + 1];
                                tk[j][ss] = sw ? fb : fa; tk[j][ss + 1] = sw ? fa : fb;
                                ti[j][ss] = sw ? ib : ia; ti[j][ss + 1] = sw ? ia : ib;
                            }
                        }
                    }
                }
            }
#pragma unroll
            for (int i = 0; i < 2; ++i)
#pragma unroll
                for (int j = 0; j < 4; ++j) acc[i][j] = {0.f, 0.f, 0.f, 0.f};
        }
    }

    // write candidates: slot layout (sp, wr*4+g4, r) -> sp*80 + (..)*5 + r
#pragma unroll
    for (int j = 0; j < 4; ++j) {
        const int col = wc * 64 + j * 16 + l16;
        const size_t base = (size_t)(q0 + col) * CPQ + sp * 80 + (wr * 4 + g4) * 5;
#pragma unroll
        for (int r = 0; r < 5; ++r) {
            keyws[base + r] = tk[j][r];
            idxws[base + r] = (unsigned short)ti[j][r];
        }
    }
}

// ---------------- fast phase 2: merge 640 -> 16, exact f64 rescore, formula ----------------
__global__ void knn_phase2(const float* __restrict__ query,
                           const float* __restrict__ mem,
                           const float* __restrict__ nsb,
                           const float* __restrict__ keyws,
                           const unsigned short* __restrict__ idxws,
                           float* __restrict__ out) {
    const int wv   = threadIdx.x >> 6;
    const int lane = threadIdx.x & 63;
    const int row  = blockIdx.x * 4 + wv;

    __shared__ int   sel[4][16];
    __shared__ float dsel[4][16];

    float    k[10];
    unsigned id[10];
    const size_t cb = (size_t)row * CPQ;
#pragma unroll
    for (int r = 0; r < 10; ++r) {
        k[r]  = keyws[cb + r * 64 + lane];
        id[r] = (unsigned)idxws[cb + r * 64 + lane];
    }

    for (int rr = 0; rr < 16; ++rr) {
        float lm = k[0];
#pragma unroll
        for (int r = 1; r < 10; ++r) lm = fminf(lm, k[r]);
        float m = lm;
#pragma unroll
        for (int off = 32; off > 0; off >>= 1) m = fminf(m, __shfl_xor(m, off));
        const unsigned long long bal = __ballot(lm == m);
        const bool win = (lane == (int)(__ffsll((long long)bal) - 1));
        unsigned sid = 0; bool done = false;
#pragma unroll
        for (int r = 0; r < 10; ++r) {
            const bool c = win && !done && (k[r] == m);
            sid  = c ? id[r] : sid;
            k[r] = c ? 3.4e38f : k[r];
            done = done || c;
        }
        if (win) sel[wv][rr] = (int)sid;
    }
    __syncthreads();

    // exact rescore: 4 lanes per candidate, f64 accumulation of (q-m)^2
    const int c = lane >> 2, sub = lane & 3;
    const int mi = sel[wv][c];
    const float4* qp = reinterpret_cast<const float4*>(query + (size_t)row * DIM) + sub * 64;
    const float4* mp = reinterpret_cast<const float4*>(mem + (size_t)mi * DIM) + sub * 64;
    double acc = 0.0;
#pragma unroll 4
    for (int i = 0; i < 64; ++i) {
        const float4 q4 = qp[i];
        const float4 m4 = mp[i];
        const double d0 = (double)q4.x - (double)m4.x;
        const double d1 = (double)q4.y - (double)m4.y;
        const double d2 = (double)q4.z - (double)m4.z;
        const double d3 = (double)q4.w - (double)m4.w;
        acc += d0 * d0 + d1 * d1 + d2 * d2 + d3 * d3;
    }
    acc += __shfl_xor(acc, 1);
    acc += __shfl_xor(acc, 2);
    if (sub == 0) dsel[wv][c] = (float)sqrt(fmax(acc, 1e-12));
    __syncthreads();

    if (lane == 0) {
        float dv[16]; int di[16];
#pragma unroll
        for (int i = 0; i < 16; ++i) { dv[i] = dsel[wv][i]; di[i] = sel[wv][i]; }
        float kd[KNN]; int ki[KNN];
#pragma unroll
        for (int r = 0; r < KNN; ++r) {
            float bv = 3.4e38f; int bi = 0x7fffffff; int bp = -1;
#pragma unroll
            for (int i = 0; i < 16; ++i) {
                const bool better = (dv[i] < bv) || (dv[i] == bv && di[i] < bi);
                if (better) { bv = dv[i]; bi = di[i]; bp = i; }
            }
            kd[r] = bv; ki[r] = bi;
#pragma unroll
            for (int i = 0; i < 16; ++i) if (i == bp) dv[i] = 3.4e38f;
        }
        double dmin = (double)kd[0];
#pragma unroll
        for (int r = 1; r < KNN; ++r) dmin = fmin(dmin, (double)kd[r]);
        double w[KNN], se = 0.0, wd = 0.0, sd = 0.0, sc = 0.0;
#pragma unroll
        for (int r = 0; r < KNN; ++r) {
            w[r] = exp(-((double)kd[r] - dmin));
            se += w[r];
            sd += (double)kd[r];
            sc += (double)nsb[ki[r]];
        }
#pragma unroll
        for (int r = 0; r < KNN; ++r) wd += w[r] * (double)kd[r];
        wd /= se;
        sc /= (double)KNN;
        const double nd   = wd / fmax(sc, 1e-6);
        const double mean = sd / (double)KNN;
        double var = 0.0;
#pragma unroll
        for (int r = 0; r < KNN; ++r) { const double dd = (double)kd[r] - mean; var += dd * dd; }
        var /= (double)KNN;
        const double cons = sqrt(var) / fmax(mean, 1e-6);
        out[row] = (float)(nd * (1.0 + 0.5 * cons));
    }
}

// ================= fallback path (round-1, proven; used if ws too small) =================
typedef float f32x4fb_t __attribute__((ext_vector_type(4)));

__global__ void fb_m2_kernel(const float* __restrict__ mem, float* __restrict__ m2) {
    const int row  = blockIdx.x * 4 + (threadIdx.x >> 6);
    const int lane = threadIdx.x & 63;
    const float4* p = reinterpret_cast<const float4*>(mem + (size_t)row * DIM) + lane;
    float s = 0.f;
#pragma unroll
    for (int i = 0; i < 4; ++i) {
        const float4 v = p[i * 64];
        s += v.x * v.x + v.y * v.y + v.z * v.z + v.w * v.w;
    }
#pragma unroll
    for (int off = 32; off > 0; off >>= 1) s += __shfl_down(s, off);
    if (lane == 0) m2[row] = s;
}

__launch_bounds__(512, 1)
__global__ void fb_knn_phase1(const float* __restrict__ query,
                              const float* __restrict__ mem,
                              const float* __restrict__ m2,
                              float* __restrict__ wkey,
                              int* __restrict__ widx) {
    __shared__ alignas(16) __bf16 Qs[128][72];
    __shared__ alignas(16) __bf16 Ms[128][72];
    __shared__ float D2[128][129];
    __shared__ float m2s[128];

    const int t    = threadIdx.x;
    const int lane = t & 63;
    const int wave = t >> 6;
    const int wr   = wave >> 1;
    const int wc   = wave & 1;

    const int mb    = blockIdx.x & 63;
    const int sp    = blockIdx.x >> 6;
    const int q0    = mb * 128;
    const int mbase = sp * 4096;

    const int srow = t & 127;
    const int sseg = t >> 7;
    const int str = t >> 2;
    const int stc = (t & 3) * 16;

    float topv[8]; int topi[8];
#pragma unroll
    for (int i = 0; i < 8; ++i) { topv[i] = 3.4e38f; topi[i] = 0; }
    float curmax = 3.4e38f;
    const f32x4fb_t zero = {0.f, 0.f, 0.f, 0.f};

    for (int tile = 0; tile < 32; ++tile) {
        const int c0 = mbase + tile * 128;
        if (t < 128) m2s[t] = m2[c0 + t];
        f32x4fb_t acc[2][4];
#pragma unroll
        for (int i = 0; i < 2; ++i)
#pragma unroll
            for (int j = 0; j < 4; ++j) acc[i][j] = zero;

        for (int k0 = 0; k0 < DIM; k0 += 64) {
            {
                const float4* qp = reinterpret_cast<const float4*>(query + (size_t)(q0 + str) * DIM + k0 + stc);
                const float4 a0 = qp[0], a1 = qp[1], a2 = qp[2], a3 = qp[3];
                const float4* mp = reinterpret_cast<const float4*>(mem + (size_t)(c0 + str) * DIM + k0 + stc);
                const float4 b0 = mp[0], b1 = mp[1], b2 = mp[2], b3 = mp[3];
                bf16x8_t qa, qb, ma, mbv;
                qa[0] = (__bf16)a0.x; qa[1] = (__bf16)a0.y; qa[2] = (__bf16)a0.z; qa[3] = (__bf16)a0.w;
                qa[4] = (__bf16)a1.x; qa[5] = (__bf16)a1.y; qa[6] = (__bf16)a1.z; qa[7] = (__bf16)a1.w;
                qb[0] = (__bf16)a2.x; qb[1] = (__bf16)a2.y; qb[2] = (__bf16)a2.z; qb[3] = (__bf16)a2.w;
                qb[4] = (__bf16)a3.x; qb[5] = (__bf16)a3.y; qb[6] = (__bf16)a3.z; qb[7] = (__bf16)a3.w;
                ma[0] = (__bf16)b0.x; ma[1] = (__bf16)b0.y; ma[2] = (__bf16)b0.z; ma[3] = (__bf16)b0.w;
                ma[4] = (__bf16)b1.x; ma[5] = (__bf16)b1.y; ma[6] = (__bf16)b1.z; ma[7] = (__bf16)b1.w;
                mbv[0] = (__bf16)b2.x; mbv[1] = (__bf16)b2.y; mbv[2] = (__bf16)b2.z; mbv[3] = (__bf16)b2.w;
                mbv[4] = (__bf16)b3.x; mbv[5] = (__bf16)b3.y; mbv[6] = (__bf16)b3.z; mbv[7] = (__bf16)b3.w;
                *reinterpret_cast<bf16x8_t*>(&Qs[str][stc])     = qa;
                *reinterpret_cast<bf16x8_t*>(&Qs[str][stc + 8]) = qb;
                *reinterpret_cast<bf16x8_t*>(&Ms[str][stc])     = ma;
                *reinterpret_cast<bf16x8_t*>(&Ms[str][stc + 8]) = mbv;
            }
            __syncthreads();
#pragma unroll
            for (int kk = 0; kk < 64; kk += 32) {
                const int koff = kk + ((lane >> 4) << 3);
                const int ar   = wr * 32 + (lane & 15);
                const bf16x8_t a0 = *reinterpret_cast<const bf16x8_t*>(&Qs[ar][koff]);
                const bf16x8_t a1 = *reinterpret_cast<const bf16x8_t*>(&Qs[ar + 16][koff]);
                const int bc = wc * 64 + (lane & 15);
                const bf16x8_t b0 = *reinterpret_cast<const bf16x8_t*>(&Ms[bc][koff]);
                const bf16x8_t b1 = *reinterpret_cast<const bf16x8_t*>(&Ms[bc + 16][koff]);
                const bf16x8_t b2 = *reinterpret_cast<const bf16x8_t*>(&Ms[bc + 32][koff]);
                const bf16x8_t b3 = *reinterpret_cast<const bf16x8_t*>(&Ms[bc + 48][koff]);
                acc[0][0] = __builtin_amdgcn_mfma_f32_16x16x32_bf16(a0, b0, acc[0][0], 0, 0, 0);
                acc[0][1] = __builtin_amdgcn_mfma_f32_16x16x32_bf16(a0, b1, acc[0][1], 0, 0, 0);
                acc[0][2] = __builtin_amdgcn_mfma_f32_16x16x32_bf16(a0, b2, acc[0][2], 0, 0, 0);
                acc[0][3] = __builtin_amdgcn_mfma_f32_16x16x32_bf16(a0, b3, acc[0][3], 0, 0, 0);
                acc[1][0] = __builtin_amdgcn_mfma_f32_16x16x32_bf16(a1, b0, acc[1][0], 0, 0, 0);
                acc[1][1] = __builtin_amdgcn_mfma_f32_16x16x32_bf16(a1, b1, acc[1][1], 0, 0, 0);
                acc[1][2] = __builtin_amdgcn_mfma_f32_16x16x32_bf16(a1, b2, acc[1][2], 0, 0, 0);
                acc[1][3] = __builtin_amdgcn_mfma_f32_16x16x32_bf16(a1, b3, acc[1][3], 0, 0, 0);
            }
            __syncthreads();
        }
#pragma unroll
        for (int i = 0; i < 2; ++i) {
            const int r0 = wr * 32 + i * 16 + ((lane >> 4) << 2);
#pragma unroll
            for (int j = 0; j < 4; ++j) {
                const int cc = wc * 64 + j * 16 + (lane & 15);
                const float mm = m2s[cc];
#pragma unroll
                for (int rg = 0; rg < 4; ++rg)
                    D2[r0 + rg][cc] = mm - 2.0f * acc[i][j][rg];
            }
        }
        __syncthreads();
        {
            const int gbase = c0 + sseg * 32;
#pragma unroll 8
            for (int cc = 0; cc < 32; ++cc) {
                const float key = D2[srow][sseg * 32 + cc];
                if (key < curmax) {
                    bool done = false;
#pragma unroll
                    for (int i = 0; i < 8; ++i) {
                        if (!done && topv[i] == curmax) {
                            topv[i] = key; topi[i] = gbase + cc; done = true;
                        }
                    }
                    curmax = topv[0];
#pragma unroll
                    for (int i = 1; i < 8; ++i) curmax = fmaxf(curmax, topv[i]);
                }
            }
        }
        __syncthreads();
    }
    const size_t base = ((size_t)(q0 + srow) * 4 + sp) * 32 + (size_t)sseg * 8;
#pragma unroll
    for (int j = 0; j < 8; ++j) { wkey[base + j] = topv[j]; widx[base + j] = topi[j]; }
}

__global__ void fb_knn_phase2(const float* __restrict__ query,
                              const float* __restrict__ mem,
                              const float* __restrict__ nsb,
                              const float* __restrict__ wkey,
                              const int* __restrict__ widx,
                              float* __restrict__ out) {
    const int wv   = threadIdx.x >> 6;
    const int lane = threadIdx.x & 63;
    const int row  = blockIdx.x * 4 + wv;
    __shared__ int   sel[4][16];
    __shared__ float dsel[4][16];

    const size_t cb = (size_t)row * 128;
    float k0 = wkey[cb + lane];
    float k1 = wkey[cb + 64 + lane];
    const int i0 = widx[cb + lane];
    const int i1 = widx[cb + 64 + lane];

    for (int r = 0; r < 16; ++r) {
        float m = fminf(k0, k1);
#pragma unroll
        for (int off = 32; off > 0; off >>= 1) m = fminf(m, __shfl_xor(m, off));
        const unsigned long long b0 = __ballot(k0 == m);
        const unsigned long long b1 = __ballot(k1 == m);
        if (b0) {
            if (lane == __ffsll(b0) - 1) { sel[wv][r] = i0; k0 = 3.4e38f; }
        } else {
            if (lane == __ffsll(b1) - 1) { sel[wv][r] = i1; k1 = 3.4e38f; }
        }
    }
    __syncthreads();

    const int c = lane >> 2, sub = lane & 3;
    const int mi = sel[wv][c];
    const float4* qp = reinterpret_cast<const float4*>(query + (size_t)row * DIM) + sub * 64;
    const float4* mp = reinterpret_cast<const float4*>(mem + (size_t)mi * DIM) + sub * 64;
    double acc = 0.0;
#pragma unroll 4
    for (int i = 0; i < 64; ++i) {
        const float4 q4 = qp[i];
        const float4 m4 = mp[i];
        const double d0 = (double)q4.x - (double)m4.x;
        const double d1 = (double)q4.y - (double)m4.y;
        const double d2 = (double)q4.z - (double)m4.z;
        const double d3 = (double)q4.w - (double)m4.w;
        acc += d0 * d0 + d1 * d1 + d2 * d2 + d3 * d3;
    }
    acc += __shfl_xor(acc, 1);
    acc += __shfl_xor(acc, 2);
    if (sub == 0) dsel[wv][c] = (float)sqrt(fmax(acc, 1e-12));
    __syncthreads();

    if (lane == 0) {
        float dv[16]; int di[16];
#pragma unroll
        for (int i = 0; i < 16; ++i) { dv[i] = dsel[wv][i]; di[i] = sel[wv][i]; }
        float kd[KNN]; int ki[KNN];
#pragma unroll
        for (int r = 0; r < KNN; ++r) {
            float bv = 3.4e38f; int bi = 0x7fffffff; int bp = -1;
#pragma unroll
            for (int i = 0; i < 16; ++i) {
                const bool better = (dv[i] < bv) || (dv[i] == bv && di[i] < bi);
                if (better) { bv = dv[i]; bi = di[i]; bp = i; }
            }
            kd[r] = bv; ki[r] = bi;
#pragma unroll
            for (int i = 0; i < 16; ++i) if (i == bp) dv[i] = 3.4e38f;
        }
        double dmin = (double)kd[0];
#pragma unroll
        for (int r = 1; r < KNN; ++r) dmin = fmin(dmin, (double)kd[r]);
        double w[KNN], se = 0.0, wd = 0.0, sd = 0.0, sc = 0.0;
#pragma unroll
        for (int r = 0; r < KNN; ++r) {
            w[r] = exp(-((double)kd[r] - dmin));
            se += w[r];
            sd += (double)kd[r];
            sc += (double)nsb[ki[r]];
        }
#pragma unroll
        for (int r = 0; r < KNN; ++r) wd += w[r] * (double)kd[r];
        wd /= se;
        sc /= (double)KNN;
        const double nd   = wd / fmax(sc, 1e-6);
        const double mean = sd / (double)KNN;
        double var = 0.0;
#pragma unroll
        for (int r = 0; r < KNN; ++r) { const double dd = (double)kd[r] - mean; var += dd * dd; }
        var /= (double)KNN;
        const double cons = sqrt(var) / fmax(mean, 1e-6);
        out[row] = (float)(nd * (1.0 + 0.5 * cons));
    }
}

extern "C" void kernel_launch(void* const* d_in, const int* in_sizes, int n_in,
                              void* d_out, int out_size, void* d_ws, size_t ws_size,
                              hipStream_t stream) {
    const float* query = (const float*)d_in[0];
    const float* mem   = (const float*)d_in[1];
    const float* nsb   = (const float*)d_in[2];
    float* out = (float*)d_out;
    char* ws = (char*)d_ws;

    const size_t offQ   = 0;
    const size_t offM   = offQ + (size_t)NQ * DIM * 2;      // 16 MB
    const size_t offm2  = offM + (size_t)NM * DIM * 2;      // +32 MB
    const size_t offkey = offm2 + (size_t)NM * 4;           // +64 KB
    const size_t offidx = offkey + (size_t)NQ * CPQ * 4;    // +20 MB
    const size_t need   = offidx + (size_t)NQ * CPQ * 2;    // +10 MB (~78 MB)

    if (ws_size >= need) {
        __hip_bfloat16* Qbf = (__hip_bfloat16*)(ws + offQ);
        __hip_bfloat16* Mbf = (__hip_bfloat16*)(ws + offM);
        float*          m2  = (float*)(ws + offm2);
        float*          key = (float*)(ws + offkey);
        unsigned short* idx = (unsigned short*)(ws + offidx);

        hipLaunchKernelGGL(cvt_bf16_kernel, dim3(NQ * DIM / 8 / 256), dim3(256), 0, stream,
                           query, Qbf, NQ * DIM / 8);
        hipLaunchKernelGGL(cvt_m2_kernel, dim3(NM / 4), dim3(256), 0, stream, mem, Mbf, m2);
        hipLaunchKernelGGL(knn_phase1, dim3((NQ / 128) * SPLITS), dim3(TPB1), 0, stream,
                           Qbf, Mbf, m2, key, idx);
        hipLaunchKernelGGL(knn_phase2, dim3(NQ / 4), dim3(256), 0, stream,
                           query, mem, nsb, key, idx, out);
    } else {
        float* wkey = (float*)ws;                              // 4 MB
        int*   widx = (int*)(ws + (size_t)NQ * 128 * 4);       // 4 MB
        float* m2   = (float*)(ws + (size_t)NQ * 128 * 8);     // 64 KB
        hipLaunchKernelGGL(fb_m2_kernel, dim3(NM / 4), dim3(256), 0, stream, mem, m2);
        hipLaunchKernelGGL(fb_knn_phase1, dim3((NQ / 128) * 4), dim3(512), 0, stream,
                           query, mem, m2, wkey, widx);
        hipLaunchKernelGGL(fb_knn_phase2, dim3(NQ / 4), dim3(256), 0, stream,
                           query, mem, nsb, wkey, widx, out);
    }
}